// Round 2
// baseline (299.124 us; speedup 1.0000x reference)
//
#include <hip/hip_runtime.h>

#define T_LEN 4096
#define DHEAD 64
#define WINSZ 128
#define KVLEN 256
#define NWIN 32
#define NBH 64
#define FLTMAX 3.402823466e38f

typedef float f32x4 __attribute__((ext_vector_type(4)));
typedef short s16x8 __attribute__((ext_vector_type(8)));

// float -> bf16 bits, round-to-nearest-even (finite inputs only)
__device__ __forceinline__ unsigned short f2b(float x) {
  unsigned u = __builtin_bit_cast(unsigned, x);
  u += 0x7fffu + ((u >> 16) & 1u);
  return (unsigned short)(u >> 16);
}

// RoPE table: tab[0 .. T*32) = cos, tab[T*32 .. 2*T*32) = sin
__global__ void rope_tab_kernel(float* __restrict__ tab) {
  const int idx = blockIdx.x * 256 + threadIdx.x;
  if (idx >= T_LEN * 32) return;
  const int t = idx >> 5;
  const int i = idx & 31;
  const float freq = powf(10000.0f, -(float)i / 32.0f);
  float s, c;
  sincosf((float)t * freq, &s, &c);
  tab[idx] = c;
  tab[T_LEN * 32 + idx] = s;
}

// One block per (batch-head, window). 256 threads = 4 waves.
// Wave wv owns query rows [32*wv, 32*wv+32) of the window.
// MFMA 16x16x32 bf16 layouts (m89-verified C/D; standard A/B):
//   A: m = lane&15, k = (lane>>4)*8 + j   (8 contiguous bf16)
//   B: n = lane&15, k = (lane>>4)*8 + j
//   D: n = lane&15, m = (lane>>4)*4 + reg
__global__ __launch_bounds__(256, 1) void lattn_kernel(
    const float* __restrict__ qg, const float* __restrict__ kg,
    const float* __restrict__ vg, const float* __restrict__ tab,
    float* __restrict__ outg) {
  // XOR-swizzle: logical [row][col] bf16, ushort index = row*C + (col ^ ((row&7)<<3))
  __shared__ __align__(16) unsigned short Kl[KVLEN * DHEAD];   // 32 KB, K rope'd
  __shared__ __align__(16) unsigned short Vt[DHEAD * KVLEN];   // 32 KB, V transposed
  __shared__ __align__(16) unsigned short Pl[WINSZ * KVLEN];   // 64 KB, softmax probs

  const int bid = blockIdx.x;
  const int win = bid & (NWIN - 1);
  const int bh  = bid >> 5;
  const int tid = threadIdx.x;
  const int lane = tid & 63;
  const int wv = tid >> 6;
  const int l15 = lane & 15;
  const int g = lane >> 4;

  const size_t base = (size_t)bh * T_LEN * DHEAD;
  const int q0 = win * WINSZ;       // first query time of window
  const int k0 = q0 - WINSZ;        // first key time (may be < 0 -> padding)
  const bool use_tab = (tab != nullptr);
  const float* ct = tab;
  const float* st = tab + T_LEN * 32;

  // ---------------- stage K: global -> RoPE -> bf16 -> swizzled LDS ----------
  {
    const int c = tid & 7;          // d-quad: d0 = 4c (covers d<32; pair at d+32)
    const int rr = tid >> 3;        // 32 rows per pass
    float fr[4];
    if (!use_tab) {
      #pragma unroll
      for (int j = 0; j < 4; ++j)
        fr[j] = powf(10000.0f, -(float)(4 * c + j) / 32.0f);
    }
    #pragma unroll
    for (int p = 0; p < 8; ++p) {
      const int kr = p * 32 + rr;   // 0..255
      const int kt = k0 + kr;
      float xa[4] = {0.f,0.f,0.f,0.f}, xb[4] = {0.f,0.f,0.f,0.f};
      float cs[4], sn[4];
      #pragma unroll
      for (int j = 0; j < 4; ++j) { cs[j] = 1.f; sn[j] = 0.f; }
      if (kt >= 0) {
        const float* kp = kg + base + (size_t)kt * DHEAD + 4 * c;
        *(float4*)xa = *(const float4*)kp;
        *(float4*)xb = *(const float4*)(kp + 32);
        if (use_tab) {
          *(float4*)cs = *(const float4*)(ct + kt * 32 + 4 * c);
          *(float4*)sn = *(const float4*)(st + kt * 32 + 4 * c);
        } else {
          #pragma unroll
          for (int j = 0; j < 4; ++j) sincosf((float)kt * fr[j], &sn[j], &cs[j]);
        }
      }
      unsigned wlo[2], whi[2];
      #pragma unroll
      for (int h = 0; h < 2; ++h) {
        const int j0 = 2 * h, j1 = 2 * h + 1;
        wlo[h] = (unsigned)f2b(xa[j0]*cs[j0] - xb[j0]*sn[j0]) |
                 ((unsigned)f2b(xa[j1]*cs[j1] - xb[j1]*sn[j1]) << 16);
        whi[h] = (unsigned)f2b(xb[j0]*cs[j0] + xa[j0]*sn[j0]) |
                 ((unsigned)f2b(xb[j1]*cs[j1] + xa[j1]*sn[j1]) << 16);
      }
      const int su = (kr & 7) << 3;
      uint2 a = {wlo[0], wlo[1]}, b = {whi[0], whi[1]};
      *(uint2*)&Kl[kr * 64 + ((4 * c) ^ su)] = a;        // d 4c..4c+3
      *(uint2*)&Kl[kr * 64 + ((4 * c + 32) ^ su)] = b;   // d 4c+32..
    }
  }

  // ---------------- stage V: global -> bf16 -> transposed swizzled LDS -------
  {
    const int c = tid & 15;         // d0 = 4c
    const int rp = tid >> 4;        // row pair
    #pragma unroll
    for (int p = 0; p < 8; ++p) {
      const int kr = (p * 16 + rp) * 2;   // even key row
      const int kt = k0 + kr;
      float va[4] = {0.f,0.f,0.f,0.f}, vb[4] = {0.f,0.f,0.f,0.f};
      if (kt >= 0)
        *(float4*)va = *(const float4*)(vg + base + (size_t)kt * DHEAD + 4 * c);
      if (kt + 1 >= 0)
        *(float4*)vb = *(const float4*)(vg + base + (size_t)(kt + 1) * DHEAD + 4 * c);
      #pragma unroll
      for (int j = 0; j < 4; ++j) {
        const int d = 4 * c + j;
        const unsigned val = (unsigned)f2b(va[j]) | ((unsigned)f2b(vb[j]) << 16);
        *(unsigned*)&Vt[d * 256 + (kr ^ ((d & 7) << 3))] = val;  // Vt[d][kr], [d][kr+1]
      }
    }
  }

  // ---------------- Q: global -> RoPE -> A-fragments in registers ------------
  // ks=0 frag holds d = 8g+j (first half), ks=1 frag holds d = 32+8g+j.
  // RoPE pair (d, d+32) is lane-local across the two frags.
  s16x8 qa[2][2];
  {
    float fr[8];
    if (!use_tab) {
      #pragma unroll
      for (int j = 0; j < 8; ++j)
        fr[j] = powf(10000.0f, -(float)(8 * g + j) / 32.0f);
    }
    #pragma unroll
    for (int mtl = 0; mtl < 2; ++mtl) {
      const int qrow = q0 + wv * 32 + mtl * 16 + l15;
      const float* qp = qg + base + (size_t)qrow * DHEAD + 8 * g;
      float xa[8], xb[8], cs[8], sn[8];
      *(float4*)&xa[0] = *(const float4*)qp;
      *(float4*)&xa[4] = *(const float4*)(qp + 4);
      *(float4*)&xb[0] = *(const float4*)(qp + 32);
      *(float4*)&xb[4] = *(const float4*)(qp + 36);
      if (use_tab) {
        const float* cp = ct + qrow * 32 + 8 * g;
        const float* sp = st + qrow * 32 + 8 * g;
        *(float4*)&cs[0] = *(const float4*)cp;
        *(float4*)&cs[4] = *(const float4*)(cp + 4);
        *(float4*)&sn[0] = *(const float4*)sp;
        *(float4*)&sn[4] = *(const float4*)(sp + 4);
      } else {
        #pragma unroll
        for (int j = 0; j < 8; ++j) sincosf((float)qrow * fr[j], &sn[j], &cs[j]);
      }
      #pragma unroll
      for (int j = 0; j < 8; ++j) {
        qa[mtl][0][j] = (short)f2b(xa[j]*cs[j] - xb[j]*sn[j]);
        qa[mtl][1][j] = (short)f2b(xb[j]*cs[j] + xa[j]*sn[j]);
      }
    }
  }

  __syncthreads();

  // ---------------- QK^T + mask + softmax -> P (bf16, unnormalized) ----------
  float inv_den[2][4];
  #pragma unroll
  for (int mtl = 0; mtl < 2; ++mtl) {
    f32x4 acc[16];
    #pragma unroll
    for (int nt = 0; nt < 16; ++nt) acc[nt] = f32x4{0.f, 0.f, 0.f, 0.f};
    #pragma unroll
    for (int nt = 0; nt < 16; ++nt) {
      const int krow = nt * 16 + l15;
      const int su = (krow & 7) << 3;
      const s16x8 b0 = *(const s16x8*)&Kl[krow * 64 + ((8 * g) ^ su)];
      const s16x8 b1 = *(const s16x8*)&Kl[krow * 64 + ((8 * g + 32) ^ su)];
      acc[nt] = __builtin_amdgcn_mfma_f32_16x16x32_bf16(qa[mtl][0], b0, acc[nt], 0, 0, 0);
      acc[nt] = __builtin_amdgcn_mfma_f32_16x16x32_bf16(qa[mtl][1], b1, acc[nt], 0, 0, 0);
    }
    const int qloc = wv * 32 + mtl * 16 + 4 * g;  // + r = local query row
    float mx[4] = {-FLTMAX, -FLTMAX, -FLTMAX, -FLTMAX};
    #pragma unroll
    for (int nt = 0; nt < 16; ++nt) {
      const int kloc = nt * 16 + l15;             // local key 0..255
      const bool pad = (win == 0) && (nt < 8);    // phantom prev window
      #pragma unroll
      for (int r = 0; r < 4; ++r) {
        const bool msk = pad || (kloc > WINSZ + qloc + r);  // key time > query time
        const float s = msk ? -FLTMAX : acc[nt][r];
        acc[nt][r] = s;
        mx[r] = fmaxf(mx[r], s);
      }
    }
    #pragma unroll
    for (int off = 1; off < 16; off <<= 1) {
      #pragma unroll
      for (int r = 0; r < 4; ++r) mx[r] = fmaxf(mx[r], __shfl_xor(mx[r], off));
    }
    float den[4] = {0.f, 0.f, 0.f, 0.f};
    #pragma unroll
    for (int nt = 0; nt < 16; ++nt) {
      #pragma unroll
      for (int r = 0; r < 4; ++r) {
        const float pv = __expf(0.125f * (acc[nt][r] - mx[r]));  // scale = e^-0.5
        acc[nt][r] = pv;
        den[r] += pv;
      }
    }
    #pragma unroll
    for (int off = 1; off < 16; off <<= 1) {
      #pragma unroll
      for (int r = 0; r < 4; ++r) den[r] += __shfl_xor(den[r], off);
    }
    #pragma unroll
    for (int r = 0; r < 4; ++r) inv_den[mtl][r] = 1.0f / den[r];
    #pragma unroll
    for (int r = 0; r < 4; ++r) {
      const int m = qloc + r;
      const int sp = (m & 7) << 3;
      #pragma unroll
      for (int nt = 0; nt < 16; ++nt)
        Pl[m * 256 + ((nt * 16 + l15) ^ sp)] = f2b(acc[nt][r]);
    }
  }

  __syncthreads();

  // ---------------- O = P @ V  (normalize in epilogue) ------------------------
  f32x4 oacc[2][4];
  #pragma unroll
  for (int mtl = 0; mtl < 2; ++mtl)
    #pragma unroll
    for (int nt = 0; nt < 4; ++nt) oacc[mtl][nt] = f32x4{0.f, 0.f, 0.f, 0.f};

  #pragma unroll
  for (int ks = 0; ks < 8; ++ks) {
    s16x8 pa[2];
    #pragma unroll
    for (int mtl = 0; mtl < 2; ++mtl) {
      const int m = wv * 32 + mtl * 16 + l15;
      pa[mtl] = *(const s16x8*)&Pl[m * 256 + ((ks * 32 + 8 * g) ^ ((m & 7) << 3))];
    }
    #pragma unroll
    for (int nt = 0; nt < 4; ++nt) {
      const int d = nt * 16 + l15;
      const s16x8 vb = *(const s16x8*)&Vt[d * 256 + ((ks * 32 + 8 * g) ^ ((d & 7) << 3))];
      oacc[0][nt] = __builtin_amdgcn_mfma_f32_16x16x32_bf16(pa[0], vb, oacc[0][nt], 0, 0, 0);
      oacc[1][nt] = __builtin_amdgcn_mfma_f32_16x16x32_bf16(pa[1], vb, oacc[1][nt], 0, 0, 0);
    }
  }

  float* op = outg + base;
  #pragma unroll
  for (int mtl = 0; mtl < 2; ++mtl) {
    #pragma unroll
    for (int r = 0; r < 4; ++r) {
      const int qrow = q0 + wv * 32 + mtl * 16 + 4 * g + r;
      const float sc = inv_den[mtl][r];
      #pragma unroll
      for (int nt = 0; nt < 4; ++nt)
        op[(size_t)qrow * DHEAD + nt * 16 + l15] = oacc[mtl][nt][r] * sc;
    }
  }
}

extern "C" void kernel_launch(void* const* d_in, const int* in_sizes, int n_in,
                              void* d_out, int out_size, void* d_ws, size_t ws_size,
                              hipStream_t stream) {
  (void)in_sizes; (void)n_in; (void)out_size;
  const float* q = (const float*)d_in[0];
  const float* k = (const float*)d_in[1];
  const float* v = (const float*)d_in[2];
  float* out = (float*)d_out;

  float* tab = nullptr;
  const size_t tab_bytes = (size_t)2 * T_LEN * 32 * sizeof(float);  // 1 MB
  if (ws_size >= tab_bytes) {
    tab = (float*)d_ws;
    rope_tab_kernel<<<dim3((T_LEN * 32 + 255) / 256), dim3(256), 0, stream>>>(tab);
  }
  lattn_kernel<<<dim3(NBH * NWIN), dim3(256), 0, stream>>>(q, k, v, tab, out);
}

// Round 5
// 242.104 us; speedup vs baseline: 1.2355x; 1.2355x over previous
//
#include <hip/hip_runtime.h>

#define T_LEN 4096
#define DHEAD 64
#define WINSZ 128
#define KVLEN 256
#define NWIN 32
#define NBH 64
#define FLTMAX 3.402823466e38f

typedef float f32x4 __attribute__((ext_vector_type(4)));
typedef short s16x8 __attribute__((ext_vector_type(8)));
typedef short s16x4 __attribute__((ext_vector_type(4)));

// float -> bf16 bits, round-to-nearest-even (finite inputs only)
__device__ __forceinline__ unsigned short f2b(float x) {
  unsigned u = __builtin_bit_cast(unsigned, x);
  u += 0x7fffu + ((u >> 16) & 1u);
  return (unsigned short)(u >> 16);
}

// RoPE table: tab[0 .. T*32) = cos, tab[T*32 .. 2*T*32) = sin
__global__ void rope_tab_kernel(float* __restrict__ tab) {
  const int idx = blockIdx.x * 256 + threadIdx.x;
  if (idx >= T_LEN * 32) return;
  const int t = idx >> 5;
  const int i = idx & 31;
  const float freq = powf(10000.0f, -(float)i / 32.0f);
  float s, c;
  sincosf((float)t * freq, &s, &c);
  tab[idx] = c;
  tab[T_LEN * 32 + idx] = s;
}

// One block per (batch-head, window). 256 threads = 4 waves.
// Wave wv owns query rows [32*wv, 32*wv+32).
// SWAPPED QK^T: mfma(A=K, B=Q) -> D: col(l15)=query, row(4g+r)=key.
// Softmax reduction (over keys) = lane-local + shfl_xor(16,32).
// PV uses custom k-mapping kappa(ks,g,j)=32ks+16*(j>>2)+4g+(j&3) so the
// A-fragment is the lane's OWN P values (zero cross-lane traffic); the V
// B-fragment uses the same kappa via two ds_read_b64 per (ks,nt).
__global__ __launch_bounds__(256, 2) void lattn_kernel(
    const float* __restrict__ qg, const float* __restrict__ kg,
    const float* __restrict__ vg, const float* __restrict__ tab,
    float* __restrict__ outg) {
  // XOR-swizzle: logical [row][col] bf16, ushort index = row*C + (col ^ ((row&7)<<3))
  __shared__ __align__(16) unsigned short Kl[KVLEN * DHEAD];   // 32 KB, K rope'd
  __shared__ __align__(16) unsigned short Vt[DHEAD * KVLEN];   // 32 KB, V transposed

  const int bid = blockIdx.x;
  const int win = bid & (NWIN - 1);
  const int bh  = bid >> 5;
  const int tid = threadIdx.x;
  const int lane = tid & 63;
  const int wv = tid >> 6;
  const int l15 = lane & 15;
  const int g = lane >> 4;

  const size_t base = (size_t)bh * T_LEN * DHEAD;
  const int q0 = win * WINSZ;       // first query time of window
  const int k0 = q0 - WINSZ;        // first key time (may be < 0 -> padding)
  const bool use_tab = (tab != nullptr);
  const float* ct = tab;
  const float* st = tab + T_LEN * 32;

  // ---------------- stage K: global -> RoPE -> bf16 -> swizzled LDS ----------
  {
    const int c = tid & 7;          // d-quad: d0 = 4c (covers d<32; pair at d+32)
    const int rr = tid >> 3;        // 32 rows per pass
    float fr[4];
    if (!use_tab) {
      #pragma unroll
      for (int j = 0; j < 4; ++j)
        fr[j] = powf(10000.0f, -(float)(4 * c + j) / 32.0f);
    }
    #pragma unroll
    for (int p = 0; p < 8; ++p) {
      const int kr = p * 32 + rr;   // 0..255
      const int kt = k0 + kr;
      float xa[4] = {0.f,0.f,0.f,0.f}, xb[4] = {0.f,0.f,0.f,0.f};
      float cs[4], sn[4];
      #pragma unroll
      for (int j = 0; j < 4; ++j) { cs[j] = 1.f; sn[j] = 0.f; }
      if (kt >= 0) {
        const float* kp = kg + base + (size_t)kt * DHEAD + 4 * c;
        *(float4*)xa = *(const float4*)kp;
        *(float4*)xb = *(const float4*)(kp + 32);
        if (use_tab) {
          *(float4*)cs = *(const float4*)(ct + kt * 32 + 4 * c);
          *(float4*)sn = *(const float4*)(st + kt * 32 + 4 * c);
        } else {
          #pragma unroll
          for (int j = 0; j < 4; ++j) sincosf((float)kt * fr[j], &sn[j], &cs[j]);
        }
      }
      unsigned wlo[2], whi[2];
      #pragma unroll
      for (int h = 0; h < 2; ++h) {
        const int j0 = 2 * h, j1 = 2 * h + 1;
        wlo[h] = (unsigned)f2b(xa[j0]*cs[j0] - xb[j0]*sn[j0]) |
                 ((unsigned)f2b(xa[j1]*cs[j1] - xb[j1]*sn[j1]) << 16);
        whi[h] = (unsigned)f2b(xb[j0]*cs[j0] + xa[j0]*sn[j0]) |
                 ((unsigned)f2b(xb[j1]*cs[j1] + xa[j1]*sn[j1]) << 16);
      }
      const int su = (kr & 7) << 3;
      uint2 a = {wlo[0], wlo[1]}, b = {whi[0], whi[1]};
      *(uint2*)&Kl[kr * 64 + ((4 * c) ^ su)] = a;        // d 4c..4c+3
      *(uint2*)&Kl[kr * 64 + ((4 * c + 32) ^ su)] = b;   // d 4c+32..
    }
  }

  // ---------------- stage V: global -> bf16 -> transposed swizzled LDS -------
  {
    const int c = tid & 15;         // d0 = 4c
    const int rp = tid >> 4;        // row pair
    #pragma unroll
    for (int p = 0; p < 8; ++p) {
      const int kr = (p * 16 + rp) * 2;   // even key row
      const int kt = k0 + kr;
      float va[4] = {0.f,0.f,0.f,0.f}, vb[4] = {0.f,0.f,0.f,0.f};
      if (kt >= 0)
        *(float4*)va = *(const float4*)(vg + base + (size_t)kt * DHEAD + 4 * c);
      if (kt + 1 >= 0)
        *(float4*)vb = *(const float4*)(vg + base + (size_t)(kt + 1) * DHEAD + 4 * c);
      #pragma unroll
      for (int j = 0; j < 4; ++j) {
        const int d = 4 * c + j;
        const unsigned val = (unsigned)f2b(va[j]) | ((unsigned)f2b(vb[j]) << 16);
        *(unsigned*)&Vt[d * 256 + (kr ^ ((d & 7) << 3))] = val;  // Vt[d][kr], [d][kr+1]
      }
    }
  }

  // ---------------- Q: global -> RoPE -> B-fragments in registers ------------
  // frag 0 holds d = 8g+j, frag 1 holds d = 32+8g+j (RoPE pair lane-local).
  s16x8 qa[2][2];
  {
    float fr[8];
    if (!use_tab) {
      #pragma unroll
      for (int j = 0; j < 8; ++j)
        fr[j] = powf(10000.0f, -(float)(8 * g + j) / 32.0f);
    }
    #pragma unroll
    for (int mtl = 0; mtl < 2; ++mtl) {
      const int qrow = q0 + wv * 32 + mtl * 16 + l15;
      const float* qp = qg + base + (size_t)qrow * DHEAD + 8 * g;
      float xa[8], xb[8], cs[8], sn[8];
      *(float4*)&xa[0] = *(const float4*)qp;
      *(float4*)&xa[4] = *(const float4*)(qp + 4);
      *(float4*)&xb[0] = *(const float4*)(qp + 32);
      *(float4*)&xb[4] = *(const float4*)(qp + 36);
      if (use_tab) {
        const float* cp = ct + qrow * 32 + 8 * g;
        const float* sp = st + qrow * 32 + 8 * g;
        *(float4*)&cs[0] = *(const float4*)cp;
        *(float4*)&cs[4] = *(const float4*)(cp + 4);
        *(float4*)&sn[0] = *(const float4*)sp;
        *(float4*)&sn[4] = *(const float4*)(sp + 4);
      } else {
        #pragma unroll
        for (int j = 0; j < 8; ++j) sincosf((float)qrow * fr[j], &sn[j], &cs[j]);
      }
      #pragma unroll
      for (int j = 0; j < 8; ++j) {
        qa[mtl][0][j] = (short)f2b(xa[j]*cs[j] - xb[j]*sn[j]);
        qa[mtl][1][j] = (short)f2b(xb[j]*cs[j] + xa[j]*sn[j]);
      }
    }
  }

  __syncthreads();   // only barrier: K/V staged; all later LDS reads are RO.

  // ---------------- QK^T (swapped) + mask + softmax -> P frags in regs -------
  // pa[mtl][ks] element j = P[query=l15][key=32ks+16*(j>>2)+4g+(j&3)] * inv_den
  s16x8 pa[2][8];
  #pragma unroll
  for (int mtl = 0; mtl < 2; ++mtl) {
    f32x4 acc[16];
    #pragma unroll
    for (int nt = 0; nt < 16; ++nt) acc[nt] = f32x4{0.f, 0.f, 0.f, 0.f};
    #pragma unroll
    for (int nt = 0; nt < 16; ++nt) {
      const int krow = nt * 16 + l15;
      const int su = (krow & 7) << 3;
      const s16x8 k0f = *(const s16x8*)&Kl[krow * 64 + ((8 * g) ^ su)];
      const s16x8 k1f = *(const s16x8*)&Kl[krow * 64 + ((8 * g + 32) ^ su)];
      acc[nt] = __builtin_amdgcn_mfma_f32_16x16x32_bf16(k0f, qa[mtl][0], acc[nt], 0, 0, 0);
      acc[nt] = __builtin_amdgcn_mfma_f32_16x16x32_bf16(k1f, qa[mtl][1], acc[nt], 0, 0, 0);
    }
    const int qloc = wv * 32 + mtl * 16 + l15;   // this lane's query row
    float mx = -FLTMAX;
    #pragma unroll
    for (int nt = 0; nt < 16; ++nt) {
      const bool pad = (win == 0) && (nt < 8);   // phantom prev window
      #pragma unroll
      for (int r = 0; r < 4; ++r) {
        const int kloc = nt * 16 + 4 * g + r;
        const bool msk = pad || (kloc > WINSZ + qloc);   // key time > query time
        const float s = msk ? -FLTMAX : acc[nt][r];
        acc[nt][r] = s;
        mx = fmaxf(mx, s);
      }
    }
    mx = fmaxf(mx, __shfl_xor(mx, 16));
    mx = fmaxf(mx, __shfl_xor(mx, 32));
    float den = 0.f;
    #pragma unroll
    for (int nt = 0; nt < 16; ++nt) {
      #pragma unroll
      for (int r = 0; r < 4; ++r) {
        const float pv = __expf(0.125f * (acc[nt][r] - mx));  // scale = e^-0.5
        acc[nt][r] = pv;
        den += pv;
      }
    }
    den += __shfl_xor(den, 16);
    den += __shfl_xor(den, 32);
    const float inv = 1.0f / den;
    #pragma unroll
    for (int ks = 0; ks < 8; ++ks) {
      #pragma unroll
      for (int j = 0; j < 4; ++j) {
        pa[mtl][ks][j]     = (short)f2b(acc[2 * ks][j] * inv);
        pa[mtl][ks][j + 4] = (short)f2b(acc[2 * ks + 1][j] * inv);
      }
    }
  }

  // ---------------- O = P @ V (same kappa mapping on B) -----------------------
  f32x4 oacc[2][4];
  #pragma unroll
  for (int mtl = 0; mtl < 2; ++mtl)
    #pragma unroll
    for (int nt = 0; nt < 4; ++nt) oacc[mtl][nt] = f32x4{0.f, 0.f, 0.f, 0.f};

  #pragma unroll
  for (int ks = 0; ks < 8; ++ks) {
    #pragma unroll
    for (int nt = 0; nt < 4; ++nt) {
      const int d = nt * 16 + l15;
      const int su = (d & 7) << 3;
      const int c1 = ks * 32 + 4 * g;
      const s16x4 v0 = *(const s16x4*)&Vt[d * 256 + (c1 ^ su)];
      const s16x4 v1 = *(const s16x4*)&Vt[d * 256 + ((c1 + 16) ^ su)];
      const s16x8 vb = __builtin_shufflevector(v0, v1, 0, 1, 2, 3, 4, 5, 6, 7);
      oacc[0][nt] = __builtin_amdgcn_mfma_f32_16x16x32_bf16(pa[0][ks], vb, oacc[0][nt], 0, 0, 0);
      oacc[1][nt] = __builtin_amdgcn_mfma_f32_16x16x32_bf16(pa[1][ks], vb, oacc[1][nt], 0, 0, 0);
    }
  }

  // D layout: col(l15)=d-tile lane, row(4g+r)=query within mtl group.
  float* op = outg + base;
  #pragma unroll
  for (int mtl = 0; mtl < 2; ++mtl) {
    #pragma unroll
    for (int r = 0; r < 4; ++r) {
      const int qrow = q0 + wv * 32 + mtl * 16 + 4 * g + r;
      #pragma unroll
      for (int nt = 0; nt < 4; ++nt)
        op[(size_t)qrow * DHEAD + nt * 16 + l15] = oacc[mtl][nt][r];
    }
  }
}

extern "C" void kernel_launch(void* const* d_in, const int* in_sizes, int n_in,
                              void* d_out, int out_size, void* d_ws, size_t ws_size,
                              hipStream_t stream) {
  (void)in_sizes; (void)n_in; (void)out_size;
  const float* q = (const float*)d_in[0];
  const float* k = (const float*)d_in[1];
  const float* v = (const float*)d_in[2];
  float* out = (float*)d_out;

  float* tab = nullptr;
  const size_t tab_bytes = (size_t)2 * T_LEN * 32 * sizeof(float);  // 1 MB
  if (ws_size >= tab_bytes) {
    tab = (float*)d_ws;
    rope_tab_kernel<<<dim3((T_LEN * 32 + 255) / 256), dim3(256), 0, stream>>>(tab);
  }
  lattn_kernel<<<dim3(NBH * NWIN), dim3(256), 0, stream>>>(q, k, v, tab, out);
}

// Round 6
// 227.286 us; speedup vs baseline: 1.3161x; 1.0652x over previous
//
#include <hip/hip_runtime.h>

#define T_LEN 4096
#define DHEAD 64
#define WINSZ 128
#define KVLEN 256
#define NWIN 32
#define NBH 64
#define FLTMAX 3.402823466e38f

typedef float f32x4 __attribute__((ext_vector_type(4)));
typedef short s16x8 __attribute__((ext_vector_type(8)));
typedef short s16x4 __attribute__((ext_vector_type(4)));

// float -> bf16 bits, round-to-nearest-even (finite inputs only)
__device__ __forceinline__ unsigned short f2b(float x) {
  unsigned u = __builtin_bit_cast(unsigned, x);
  u += 0x7fffu + ((u >> 16) & 1u);
  return (unsigned short)(u >> 16);
}

// RoPE table: tab[0 .. T*32) = cos, tab[T*32 .. 2*T*32) = sin
__global__ void rope_tab_kernel(float* __restrict__ tab) {
  const int idx = blockIdx.x * 256 + threadIdx.x;
  if (idx >= T_LEN * 32) return;
  const int t = idx >> 5;
  const int i = idx & 31;
  const float freq = powf(10000.0f, -(float)i / 32.0f);
  float s, c;
  sincosf((float)t * freq, &s, &c);
  tab[idx] = c;
  tab[T_LEN * 32 + idx] = s;
}

// One block per (batch-head, window). 512 threads = 8 waves.
// Wave wv owns query rows [16*wv, 16*wv+16).
// SWAPPED QK^T: mfma(A=K, B=Q) -> D: col(l15)=query, row(4g+r)=key.
// Softmax reduction (over keys) = lane-local + shfl_xor(16,32).
// PV uses custom k-mapping kappa(ks,g,j)=32ks+16*(j>>2)+4g+(j&3) so the
// A-fragment is the lane's OWN P values (zero cross-lane traffic); the V
// B-fragment uses the same kappa via two ds_read_b64 per (ks,nt).
__global__ __launch_bounds__(512, 4) void lattn_kernel(
    const float* __restrict__ qg, const float* __restrict__ kg,
    const float* __restrict__ vg, const float* __restrict__ tab,
    float* __restrict__ outg) {
  // XOR-swizzle: logical [row][col] bf16, ushort index = row*C + (col ^ ((row&7)<<3))
  __shared__ __align__(16) unsigned short Kl[KVLEN * DHEAD];   // 32 KB, K rope'd
  __shared__ __align__(16) unsigned short Vt[DHEAD * KVLEN];   // 32 KB, V transposed

  const int bid = blockIdx.x;
  const int win = bid & (NWIN - 1);
  const int bh  = bid >> 5;
  const int tid = threadIdx.x;
  const int lane = tid & 63;
  const int wv = tid >> 6;          // 0..7
  const int l15 = lane & 15;
  const int g = lane >> 4;

  const size_t base = (size_t)bh * T_LEN * DHEAD;
  const int q0 = win * WINSZ;       // first query time of window
  const int k0 = q0 - WINSZ;        // first key time (may be < 0 -> padding)
  const bool use_tab = (tab != nullptr);
  const float* ct = tab;
  const float* st = tab + T_LEN * 32;

  // ---------------- stage K: global -> RoPE -> bf16 -> swizzled LDS ----------
  {
    const int c = tid & 7;          // d-quad: d0 = 4c (covers d<32; pair at d+32)
    const int rr = tid >> 3;        // 64 rows per pass
    float fr[4];
    if (!use_tab) {
      #pragma unroll
      for (int j = 0; j < 4; ++j)
        fr[j] = powf(10000.0f, -(float)(4 * c + j) / 32.0f);
    }
    #pragma unroll
    for (int p = 0; p < 4; ++p) {
      const int kr = p * 64 + rr;   // 0..255
      const int kt = k0 + kr;
      float xa[4] = {0.f,0.f,0.f,0.f}, xb[4] = {0.f,0.f,0.f,0.f};
      float cs[4], sn[4];
      #pragma unroll
      for (int j = 0; j < 4; ++j) { cs[j] = 1.f; sn[j] = 0.f; }
      if (kt >= 0) {
        const float* kp = kg + base + (size_t)kt * DHEAD + 4 * c;
        *(float4*)xa = *(const float4*)kp;
        *(float4*)xb = *(const float4*)(kp + 32);
        if (use_tab) {
          *(float4*)cs = *(const float4*)(ct + kt * 32 + 4 * c);
          *(float4*)sn = *(const float4*)(st + kt * 32 + 4 * c);
        } else {
          #pragma unroll
          for (int j = 0; j < 4; ++j) sincosf((float)kt * fr[j], &sn[j], &cs[j]);
        }
      }
      unsigned wlo[2], whi[2];
      #pragma unroll
      for (int h = 0; h < 2; ++h) {
        const int j0 = 2 * h, j1 = 2 * h + 1;
        wlo[h] = (unsigned)f2b(xa[j0]*cs[j0] - xb[j0]*sn[j0]) |
                 ((unsigned)f2b(xa[j1]*cs[j1] - xb[j1]*sn[j1]) << 16);
        whi[h] = (unsigned)f2b(xb[j0]*cs[j0] + xa[j0]*sn[j0]) |
                 ((unsigned)f2b(xb[j1]*cs[j1] + xa[j1]*sn[j1]) << 16);
      }
      const int su = (kr & 7) << 3;
      uint2 a = {wlo[0], wlo[1]}, b = {whi[0], whi[1]};
      *(uint2*)&Kl[kr * 64 + ((4 * c) ^ su)] = a;        // d 4c..4c+3
      *(uint2*)&Kl[kr * 64 + ((4 * c + 32) ^ su)] = b;   // d 4c+32..
    }
  }

  // ---------------- stage V: global -> bf16 -> transposed swizzled LDS -------
  {
    const int c = tid & 15;         // d0 = 4c
    const int rp = tid >> 4;        // row pair, 32 per pass
    #pragma unroll
    for (int p = 0; p < 4; ++p) {
      const int kr = (p * 32 + rp) * 2;   // even key row
      const int kt = k0 + kr;
      float va[4] = {0.f,0.f,0.f,0.f}, vb[4] = {0.f,0.f,0.f,0.f};
      if (kt >= 0)
        *(float4*)va = *(const float4*)(vg + base + (size_t)kt * DHEAD + 4 * c);
      if (kt + 1 >= 0)
        *(float4*)vb = *(const float4*)(vg + base + (size_t)(kt + 1) * DHEAD + 4 * c);
      #pragma unroll
      for (int j = 0; j < 4; ++j) {
        const int d = 4 * c + j;
        const unsigned val = (unsigned)f2b(va[j]) | ((unsigned)f2b(vb[j]) << 16);
        *(unsigned*)&Vt[d * 256 + (kr ^ ((d & 7) << 3))] = val;  // Vt[d][kr], [d][kr+1]
      }
    }
  }

  // ---------------- Q: global -> RoPE -> B-fragments in registers ------------
  // frag 0 holds d = 8g+j, frag 1 holds d = 32+8g+j (RoPE pair lane-local).
  s16x8 qa[2];
  {
    const int qrow = q0 + wv * 16 + l15;
    const float* qp = qg + base + (size_t)qrow * DHEAD + 8 * g;
    float xa[8], xb[8], cs[8], sn[8];
    *(float4*)&xa[0] = *(const float4*)qp;
    *(float4*)&xa[4] = *(const float4*)(qp + 4);
    *(float4*)&xb[0] = *(const float4*)(qp + 32);
    *(float4*)&xb[4] = *(const float4*)(qp + 36);
    if (use_tab) {
      const float* cp = ct + qrow * 32 + 8 * g;
      const float* sp = st + qrow * 32 + 8 * g;
      *(float4*)&cs[0] = *(const float4*)cp;
      *(float4*)&cs[4] = *(const float4*)(cp + 4);
      *(float4*)&sn[0] = *(const float4*)sp;
      *(float4*)&sn[4] = *(const float4*)(sp + 4);
    } else {
      #pragma unroll
      for (int j = 0; j < 8; ++j) {
        const float f = powf(10000.0f, -(float)(8 * g + j) / 32.0f);
        sincosf((float)qrow * f, &sn[j], &cs[j]);
      }
    }
    #pragma unroll
    for (int j = 0; j < 8; ++j) {
      qa[0][j] = (short)f2b(xa[j]*cs[j] - xb[j]*sn[j]);
      qa[1][j] = (short)f2b(xb[j]*cs[j] + xa[j]*sn[j]);
    }
  }

  __syncthreads();   // only barrier: K/V staged; all later LDS reads are RO.

  // ---------------- QK^T (swapped) + mask + softmax -> P frags in regs -------
  // pa[ks] element j = P[query=l15][key=32ks+16*(j>>2)+4g+(j&3)] * inv_den
  s16x8 pa[8];
  {
    f32x4 acc[16];
    #pragma unroll
    for (int nt = 0; nt < 16; ++nt) acc[nt] = f32x4{0.f, 0.f, 0.f, 0.f};
    #pragma unroll
    for (int nt = 0; nt < 16; ++nt) {
      const int krow = nt * 16 + l15;
      const int su = (krow & 7) << 3;
      const s16x8 k0f = *(const s16x8*)&Kl[krow * 64 + ((8 * g) ^ su)];
      const s16x8 k1f = *(const s16x8*)&Kl[krow * 64 + ((8 * g + 32) ^ su)];
      acc[nt] = __builtin_amdgcn_mfma_f32_16x16x32_bf16(k0f, qa[0], acc[nt], 0, 0, 0);
      acc[nt] = __builtin_amdgcn_mfma_f32_16x16x32_bf16(k1f, qa[1], acc[nt], 0, 0, 0);
    }
    const int qloc = wv * 16 + l15;   // this lane's query row in window
    float mx = -FLTMAX;
    #pragma unroll
    for (int nt = 0; nt < 16; ++nt) {
      const bool pad = (win == 0) && (nt < 8);   // phantom prev window
      #pragma unroll
      for (int r = 0; r < 4; ++r) {
        const int kloc = nt * 16 + 4 * g + r;
        const bool msk = pad || (kloc > WINSZ + qloc);   // key time > query time
        const float s = msk ? -FLTMAX : acc[nt][r];
        acc[nt][r] = s;
        mx = fmaxf(mx, s);
      }
    }
    mx = fmaxf(mx, __shfl_xor(mx, 16));
    mx = fmaxf(mx, __shfl_xor(mx, 32));
    float den = 0.f;
    #pragma unroll
    for (int nt = 0; nt < 16; ++nt) {
      #pragma unroll
      for (int r = 0; r < 4; ++r) {
        const float pv = __expf(0.125f * (acc[nt][r] - mx));  // scale = e^-0.5
        acc[nt][r] = pv;
        den += pv;
      }
    }
    den += __shfl_xor(den, 16);
    den += __shfl_xor(den, 32);
    const float inv = 1.0f / den;
    #pragma unroll
    for (int ks = 0; ks < 8; ++ks) {
      #pragma unroll
      for (int j = 0; j < 4; ++j) {
        pa[ks][j]     = (short)f2b(acc[2 * ks][j] * inv);
        pa[ks][j + 4] = (short)f2b(acc[2 * ks + 1][j] * inv);
      }
    }
  }

  // ---------------- O = P @ V (same kappa mapping on B) -----------------------
  f32x4 oacc[4];
  #pragma unroll
  for (int nt = 0; nt < 4; ++nt) oacc[nt] = f32x4{0.f, 0.f, 0.f, 0.f};

  #pragma unroll
  for (int ks = 0; ks < 8; ++ks) {
    #pragma unroll
    for (int nt = 0; nt < 4; ++nt) {
      const int d = nt * 16 + l15;
      const int su = (d & 7) << 3;
      const int c1 = ks * 32 + 4 * g;
      const s16x4 v0 = *(const s16x4*)&Vt[d * 256 + (c1 ^ su)];
      const s16x4 v1 = *(const s16x4*)&Vt[d * 256 + ((c1 + 16) ^ su)];
      const s16x8 vb = __builtin_shufflevector(v0, v1, 0, 1, 2, 3, 4, 5, 6, 7);
      oacc[nt] = __builtin_amdgcn_mfma_f32_16x16x32_bf16(pa[ks], vb, oacc[nt], 0, 0, 0);
    }
  }

  // D layout: col(l15)=d-tile lane, row(4g+r)=query within wave group.
  float* op = outg + base;
  #pragma unroll
  for (int r = 0; r < 4; ++r) {
    const int qrow = q0 + wv * 16 + 4 * g + r;
    #pragma unroll
    for (int nt = 0; nt < 4; ++nt)
      op[(size_t)qrow * DHEAD + nt * 16 + l15] = oacc[nt][r];
  }
}

extern "C" void kernel_launch(void* const* d_in, const int* in_sizes, int n_in,
                              void* d_out, int out_size, void* d_ws, size_t ws_size,
                              hipStream_t stream) {
  (void)in_sizes; (void)n_in; (void)out_size;
  const float* q = (const float*)d_in[0];
  const float* k = (const float*)d_in[1];
  const float* v = (const float*)d_in[2];
  float* out = (float*)d_out;

  float* tab = nullptr;
  const size_t tab_bytes = (size_t)2 * T_LEN * 32 * sizeof(float);  // 1 MB
  if (ws_size >= tab_bytes) {
    tab = (float*)d_ws;
    rope_tab_kernel<<<dim3((T_LEN * 32 + 255) / 256), dim3(256), 0, stream>>>(tab);
  }
  lattn_kernel<<<dim3(NBH * NWIN), dim3(512), 0, stream>>>(q, k, v, tab, out);
}